// Round 10
// baseline (391.833 us; speedup 1.0000x reference)
//
#include <hip/hip_runtime.h>
#include <hip/hip_bf16.h>
#include <math.h>

// Dims fixed by setup_inputs: d_model=1024, d_inner=2048, d_state=16,
// d_conv=4, dt_rank=64, B=2, L=1024. Tokens T = 2048.
#define DM 1024
#define DI 2048
#define DS 16
#define DTR 64
#define NB 2
#define LL 1024
#define TT (NB*LL)
#define SCH 16            // scan chunk length -> 1024 blocks -> 4/CU
#define NCH (LL/SCH)      // 64 chunks per sequence
#define NPMIN 1024        // gemm3_reduce block count (TT*128/256)

typedef unsigned short u16;
typedef __attribute__((ext_vector_type(8))) short bf16x8;
typedef __attribute__((ext_vector_type(4))) float f32x4;

#define LOG2E 1.4426950408889634f

__device__ inline u16 f2bf(float f) {   // RNE f32->bf16
  union { float f; unsigned u; } c; c.f = f;
  unsigned u = c.u;
  return (u16)((u + 0x7fffu + ((u >> 16) & 1u)) >> 16);
}
__device__ inline float bf2f(u16 u) {
  union { unsigned u; float f; } c; c.u = ((unsigned)u) << 16;
  return c.f;
}

#define GLDS16(g, l) __builtin_amdgcn_global_load_lds( \
    (const __attribute__((address_space(1))) unsigned int*)(g), \
    (__attribute__((address_space(3))) unsigned int*)(l), 16, 0, 0)

// ---------------------------------------------------------------------------
// bf16 MFMA GEMM: C[M,N] = A[M,K]bf16 @ B[N,K]bf16^T. lda=ldb=K.
// kpb = K per z-block (split-K planes at C + z*M*N).
// EPI=1: clip(softplus(v+bias[col]),1e-4,20).  OB=1: store bf16, else fp32.
// NOTE (R8/R9 post-mortem): OB=1 on the K=64 GEMM5 caused a ~120 µs/iter
// regression (exact-8192KB-write dispatch, all pipes idle). Keep dlt fp32.
// ---------------------------------------------------------------------------
template<int BM, int BN, int EPI, int OB>
__global__ __launch_bounds__(256) void gemm_bf16(
    const u16* __restrict__ A, const u16* __restrict__ B,
    void* __restrict__ Cv, int M, int N, int K, int kpb,
    const float* __restrict__ bias) {
  constexpr int WAVES_M = BM / 64;
  constexpr int WAVES_N = 4 / WAVES_M;
  constexpr int WTM = 4;
  constexpr int WTN = BN / (WAVES_N * 16);
  constexpr int ASLABS = BM / 16;
  constexpr int SLABS = (BM + BN) / 16;
  constexpr int SPW = SLABS / 4;
  __shared__ u16 As[BM * 32];
  __shared__ u16 Bs[BN * 32];
  const int tid = threadIdx.x;
  const int wave = tid >> 6;
  const int lane = tid & 63;
  const int bm = blockIdx.y * BM;
  const int bn = blockIdx.x * BN;
  const int wm = (wave / WAVES_N) * 64;
  const int wn = (wave % WAVES_N) * (WTN * 16);
  const int r4 = lane >> 2;
  const int kc = (lane & 3) * 8;
  const int fr = lane & 15;
  const int fq = lane >> 4;
  const int koff = blockIdx.z * kpb;
  float* C = (float*)Cv + (size_t)blockIdx.z * M * N;
  u16* C16 = (u16*)Cv;

  f32x4 acc[WTM][WTN];
#pragma unroll
  for (int i = 0; i < WTM; ++i)
#pragma unroll
    for (int j = 0; j < WTN; ++j) acc[i][j] = (f32x4){0.f, 0.f, 0.f, 0.f};

  for (int k0 = koff; k0 < koff + kpb; k0 += 32) {
#pragma unroll
    for (int s = wave * SPW; s < (wave + 1) * SPW; ++s) {
      if (s < ASLABS) {
        int row = s * 16 + r4;
        GLDS16(A + (size_t)(bm + row) * K + k0 + kc, &As[s * 512]);
      } else {
        int row = (s - ASLABS) * 16 + r4;
        GLDS16(B + (size_t)(bn + row) * K + k0 + kc, &Bs[(s - ASLABS) * 512]);
      }
    }
    __syncthreads();
    bf16x8 af[WTM], bf[WTN];
#pragma unroll
    for (int i = 0; i < WTM; ++i)
      af[i] = *(const bf16x8*)&As[(wm + 16 * i + fr) * 32 + fq * 8];
#pragma unroll
    for (int j = 0; j < WTN; ++j)
      bf[j] = *(const bf16x8*)&Bs[(wn + 16 * j + fr) * 32 + fq * 8];
#pragma unroll
    for (int i = 0; i < WTM; ++i)
#pragma unroll
      for (int j = 0; j < WTN; ++j)
        acc[i][j] = __builtin_amdgcn_mfma_f32_16x16x32_bf16(af[i], bf[j], acc[i][j], 0, 0, 0);
    __syncthreads();
  }

#pragma unroll
  for (int i = 0; i < WTM; ++i) {
    int row0 = bm + wm + 16 * i + fq * 4;
#pragma unroll
    for (int j = 0; j < WTN; ++j) {
      int col = bn + wn + 16 * j + fr;
#pragma unroll
      for (int r = 0; r < 4; ++r) {
        float v = acc[i][j][r];
        if (EPI == 1) {
          v += bias[col];
          float sp = (v > 20.0f) ? v : log1pf(expf(v));
          v = fminf(fmaxf(sp, 1e-4f), 20.0f);
        }
        if (OB == 1) C16[(size_t)(row0 + r) * N + col] = f2bf(v);
        else         C[(size_t)(row0 + r) * N + col] = v;
      }
    }
  }
}

// ---------------------------------------------------------------------------
// GEMM3 split-K reduce: sum 16 planes of [TT x 128]; write fp32 xdb (96 cols),
// bf16 dt_raw (cols 0..63), and per-block partial min over Bm (cols 64..79).
// ---------------------------------------------------------------------------
__global__ __launch_bounds__(256) void gemm3_reduce(
    const float* __restrict__ part, float* __restrict__ xdb,
    u16* __restrict__ dtraw_bf, float* __restrict__ pmin) {
  int i = blockIdx.x * 256 + threadIdx.x;    // TT*128
  int t = i >> 7, col = i & 127;
  float s = 0.f;
#pragma unroll
  for (int z = 0; z < 16; ++z) s += part[(size_t)z * TT * 128 + i];
  if (col < 96) xdb[t * 96 + col] = s;
  if (col < 64) dtraw_bf[t * 64 + col] = f2bf(s);
  float mn = (col >= 64 && col < 80) ? s : 3.4e38f;
#pragma unroll
  for (int o = 32; o; o >>= 1) mn = fminf(mn, __shfl_down(mn, o));
  __shared__ float sm[4];
  if ((threadIdx.x & 63) == 0) sm[threadIdx.x >> 6] = mn;
  __syncthreads();
  if (threadIdx.x == 0)
    pmin[blockIdx.x] = fminf(fminf(sm[0], sm[1]), fminf(sm[2], sm[3]));
}

// ---------------------------------------------------------------------------
// Fused bf16 casts: hs, W_in, W_out, W_x (pad to 128 rows), W_dt.
// ---------------------------------------------------------------------------
__global__ __launch_bounds__(256) void cast_all(
    const float* __restrict__ hs, const float* __restrict__ win,
    const float* __restrict__ wout, const float* __restrict__ wx,
    const float* __restrict__ wdt,
    u16* __restrict__ hs_bf, u16* __restrict__ win_bf,
    u16* __restrict__ wout_bf, u16* __restrict__ wx_bf,
    u16* __restrict__ wdt_bf) {
  int gid = blockIdx.x * 256 + threadIdx.x;  // 2,195,456 total
  const float* src; u16* dst; int off;
  if (gid < 524288)       { src = hs;   dst = hs_bf;   off = gid; }
  else if (gid < 1572864) { src = win;  dst = win_bf;  off = gid - 524288; }
  else if (gid < 2097152) { src = wout; dst = wout_bf; off = gid - 1572864; }
  else if (gid < 2146304) { src = wx;   dst = wx_bf;   off = gid - 2097152; }
  else if (gid < 2179072) { src = wdt;  dst = wdt_bf;  off = gid - 2146304; }
  else {  // zero-fill wx_bf rows 96..127
    ushort4 z4 = {0, 0, 0, 0};
    ((ushort4*)wx_bf)[49152 + gid - 2179072] = z4;
    return;
  }
  float4 v = ((const float4*)src)[off];
  ushort4 o;
  o.x = f2bf(v.x); o.y = f2bf(v.y); o.z = f2bf(v.z); o.w = f2bf(v.w);
  ((ushort4*)dst)[off] = o;
}

// ---------------------------------------------------------------------------
// Causal depthwise conv (k=4, pad 3) + bias + SiLU. bf16 in, bf16 out.
// ---------------------------------------------------------------------------
__global__ __launch_bounds__(256) void conv_silu4(
    const u16* __restrict__ xz, const float* __restrict__ w,
    const float* __restrict__ cb, u16* __restrict__ xc_bf) {
  int gid = blockIdx.x * 256 + threadIdx.x;  // TT*512
  int dq = (gid & 511) * 4;
  int t = gid >> 9;
  int l = t & (LL - 1);
  float wv[4][4];
#pragma unroll
  for (int j = 0; j < 4; ++j) {
    float4 ww = *(const float4*)&w[(dq + j) * 4];
    wv[j][0] = ww.x; wv[j][1] = ww.y; wv[j][2] = ww.z; wv[j][3] = ww.w;
  }
  float4 acc = *(const float4*)&cb[dq];
#pragma unroll
  for (int k = 0; k < 4; ++k) {
    int ll = l - 3 + k;
    if (ll < 0) continue;
    ushort4 xv = *(const ushort4*)&xz[(size_t)(t - 3 + k) * (2 * DI) + dq];
    acc.x += bf2f(xv.x) * wv[0][k]; acc.y += bf2f(xv.y) * wv[1][k];
    acc.z += bf2f(xv.z) * wv[2][k]; acc.w += bf2f(xv.w) * wv[3][k];
  }
  acc.x /= (1.0f + expf(-acc.x)); acc.y /= (1.0f + expf(-acc.y));
  acc.z /= (1.0f + expf(-acc.z)); acc.w /= (1.0f + expf(-acc.w));
  ushort4 o;
  o.x = f2bf(acc.x); o.y = f2bf(acc.y); o.z = f2bf(acc.z); o.w = f2bf(acc.w);
  *(ushort4*)&xc_bf[(size_t)t * DI + dq] = o;
}

// ---------------------------------------------------------------------------
// beta helper: block-wide reduce of pmin[NPMIN] -> beta (broadcast via LDS).
// ---------------------------------------------------------------------------
__device__ inline float block_beta(const float* __restrict__ pmin,
                                   float* __restrict__ sm /*[5]*/) {
  float mn = 3.4e38f;
  for (int j = threadIdx.x; j < NPMIN; j += 256) mn = fminf(mn, pmin[j]);
#pragma unroll
  for (int o = 32; o; o >>= 1) mn = fminf(mn, __shfl_down(mn, o));
  if ((threadIdx.x & 63) == 0) sm[threadIdx.x >> 6] = mn;
  __syncthreads();
  if (threadIdx.x == 0)
    sm[4] = fmaxf(0.0f, -fminf(fminf(sm[0], sm[1]), fminf(sm[2], sm[3])));
  __syncthreads();
  return sm[4];
}

// ---------------------------------------------------------------------------
// Chunked selective scan, SCH=16 (1024 blocks/pass -> 4/CU). 3 kernels.
// delta is fp32 (bf16 delta regressed — see gemm_bf16 note).
// ---------------------------------------------------------------------------
__global__ __launch_bounds__(256) void scan_pass1(
    const float* __restrict__ delta, const u16* __restrict__ xc_bf,
    const float* __restrict__ xdb, const float* __restrict__ A_log,
    const float* __restrict__ pmin,
    float* __restrict__ hend, float* __restrict__ Ssum) {
  const int d = blockIdx.x * 256 + threadIdx.x;
  const int c = blockIdx.y;
  const int b = blockIdx.z;
  __shared__ float Bsh[SCH][16];
  __shared__ float smb[5];
  const float beta = block_beta(pmin, smb);
  const int t0 = b * LL + c * SCH;
  {
    int i = threadIdx.x;
    int tt = i >> 4, n = i & 15;
    Bsh[tt][n] = xdb[(size_t)(t0 + tt) * 96 + 64 + n] + beta;
  }
  __syncthreads();
  float Av2[16];
#pragma unroll
  for (int n = 0; n < 16; ++n) Av2[n] = expf(A_log[d * 16 + n]) * LOG2E;
  float h[16];
#pragma unroll
  for (int n = 0; n < 16; ++n) h[n] = 0.f;
  float S = 0.f;
  for (int tt = 0; tt < SCH; ++tt) {
    int t = t0 + tt;
    float dv = delta[(size_t)t * DI + d];
    float xv = bf2f(xc_bf[(size_t)t * DI + d]);
    float dx = dv * xv;
    S += dv;
#pragma unroll
    for (int n = 0; n < 16; ++n) {
      float a = __builtin_amdgcn_exp2f(-dv * Av2[n]);
      h[n] = a * h[n] + dx * Bsh[tt][n];
    }
  }
  size_t base = (((size_t)(b * NCH + c) * DI) + d) * 16;
#pragma unroll
  for (int n = 0; n < 16; ++n) hend[base + n] = h[n];
  Ssum[((size_t)(b * NCH + c) * DI) + d] = S;
}

__global__ __launch_bounds__(256) void scan_pass2(
    float* __restrict__ hend, const float* __restrict__ Ssum,
    const float* __restrict__ A_log) {
  int gid = blockIdx.x * 256 + threadIdx.x;   // 65536
  int n = gid & 15;
  int d = (gid >> 4) & (DI - 1);
  int b = gid >> 15;
  float Av2 = expf(A_log[d * 16 + n]) * LOG2E;
  float H = 0.f;
  for (int c = 0; c < NCH; ++c) {
    size_t cb = ((size_t)(b * NCH + c) * DI) + d;
    float hl = hend[cb * 16 + n];
    float p = __builtin_amdgcn_exp2f(-Av2 * Ssum[cb]);
    hend[cb * 16 + n] = H;
    H = p * H + hl;
  }
}

__global__ __launch_bounds__(256) void scan_pass3(
    const float* __restrict__ delta, const u16* __restrict__ xc_bf,
    const float* __restrict__ xdb, const u16* __restrict__ xz_bf,
    const float* __restrict__ A_log, const float* __restrict__ Dp,
    const float* __restrict__ pmin, const float* __restrict__ hstart,
    u16* __restrict__ ybf) {
  const int d = blockIdx.x * 256 + threadIdx.x;
  const int c = blockIdx.y;
  const int b = blockIdx.z;
  __shared__ float Bsh[SCH][16];
  __shared__ float Csh[SCH][16];
  __shared__ float smb[5];
  const float beta = block_beta(pmin, smb);
  const int t0 = b * LL + c * SCH;
  {
    int i = threadIdx.x;
    int tt = i >> 4, n = i & 15;
    size_t row = (size_t)(t0 + tt) * 96;
    Bsh[tt][n] = xdb[row + 64 + n] + beta;
    Csh[tt][n] = xdb[row + 80 + n];
  }
  __syncthreads();
  float Av2[16];
#pragma unroll
  for (int n = 0; n < 16; ++n) Av2[n] = expf(A_log[d * 16 + n]) * LOG2E;
  float h[16];
  size_t base = (((size_t)(b * NCH + c) * DI) + d) * 16;
#pragma unroll
  for (int n = 0; n < 16; ++n) h[n] = hstart[base + n];
  const float Dd = Dp[d];
  for (int tt = 0; tt < SCH; ++tt) {
    int t = t0 + tt;
    float dv = delta[(size_t)t * DI + d];
    float xv = bf2f(xc_bf[(size_t)t * DI + d]);
    float dx = dv * xv;
    float yv = 0.f;
#pragma unroll
    for (int n = 0; n < 16; ++n) {
      float a = __builtin_amdgcn_exp2f(-dv * Av2[n]);
      h[n] = a * h[n] + dx * Bsh[tt][n];
      yv += h[n] * Csh[tt][n];
    }
    float zv = bf2f(xz_bf[(size_t)t * (2 * DI) + DI + d]);
    float out = (yv + xv * Dd) * (zv / (1.0f + expf(-zv)));
    ybf[(size_t)t * DI + d] = f2bf(out);
  }
}

extern "C" void kernel_launch(void* const* d_in, const int* in_sizes, int n_in,
                              void* d_out, int out_size, void* d_ws, size_t ws_size,
                              hipStream_t stream) {
  const float* hs      = (const float*)d_in[0];
  const float* W_in    = (const float*)d_in[1];
  const float* conv_w  = (const float*)d_in[2];
  const float* conv_b  = (const float*)d_in[3];
  const float* W_x     = (const float*)d_in[4];
  const float* W_dt    = (const float*)d_in[5];
  const float* dt_bias = (const float*)d_in[6];
  const float* W_out   = (const float*)d_in[7];
  const float* A_log   = (const float*)d_in[8];
  const float* Dp      = (const float*)d_in[9];
  float* out = (float*)d_out;

  float* ws       = (float*)d_ws;
  float* xz_bfR   = ws;                                  // 4,194,304 f
  float* xcv_bfR  = xz_bfR + (size_t)TT * 2 * DI / 2;    // 2,097,152 f
  float* xdb      = xcv_bfR + (size_t)TT * DI / 2;       //   196,608 f
  float* dlt      = xdb + (size_t)TT * 96;               // 4,194,304 f (fp32; = 16 planes TT*128)
  float* pmin     = dlt + (size_t)TT * DI;               //     1,024 f
  float* hend     = pmin + 1024;                         // 4,194,304 f
  float* Ssum     = hend + (size_t)NB * NCH * DI * 16;   //   262,144 f
  float* hs_bfR   = Ssum + (size_t)NB * NCH * DI;        // 1,048,576 f
  float* win_bfR  = hs_bfR + (size_t)TT * DM / 2;        // 2,097,152 f
  float* wout_bfR = win_bfR + (size_t)2 * DI * DM / 2;   // 1,048,576 f
  float* wx_bfR   = wout_bfR + (size_t)DM * DI / 2;      //   131,072 f
  float* wdt_bfR  = wx_bfR + 131072;                     //    65,536 f
  float* dtraw_bfR = wdt_bfR + 65536;                    //    65,536 f

  u16* xz_bf    = (u16*)xz_bfR;
  u16* xcv_bf   = (u16*)xcv_bfR;
  u16* hs_bf    = (u16*)hs_bfR;
  u16* win_bf   = (u16*)win_bfR;
  u16* wout_bf  = (u16*)wout_bfR;
  u16* wx_bf    = (u16*)wx_bfR;
  u16* wdt_bf   = (u16*)wdt_bfR;
  u16* dtraw_bf = (u16*)dtraw_bfR;
  u16* ybf      = (u16*)win_bfR;   // aliases win_bf (dead after GEMM1)
  float* part   = dlt;             // GEMM3 planes (dead before GEMM5 writes dlt)

  dim3 blk(256);

  // 0) bf16 casts
  cast_all<<<8576, blk, 0, stream>>>(hs, W_in, W_out, W_x, W_dt,
                                     hs_bf, win_bf, wout_bf, wx_bf, wdt_bf);

  // 1) xz = hs @ W_in^T  (2048x4096x1024) bf16 MFMA -> bf16 out
  gemm_bf16<128, 128, 0, 1><<<dim3(4096 / 128, TT / 128), blk, 0, stream>>>(
      hs_bf, win_bf, xz_bf, TT, 2 * DI, DM, DM, nullptr);

  // 2) conv + silu -> xcv_bf
  conv_silu4<<<(TT * DI / 4) / 256, blk, 0, stream>>>(xz_bf, conv_w, conv_b, xcv_bf);

  // 3) x_dbl: (2048x128x2048) bf16 MFMA split-K=16 planes -> reduce (+min)
  gemm_bf16<128, 128, 0, 0><<<dim3(1, TT / 128, 16), blk, 0, stream>>>(
      xcv_bf, wx_bf, part, TT, 128, DI, 128, nullptr);
  gemm3_reduce<<<NPMIN, blk, 0, stream>>>(part, xdb, dtraw_bf, pmin);

  // 4) delta: (2048x2048x64) bf16 MFMA + softplus/clip epilogue -> fp32 dlt
  gemm_bf16<128, 128, 1, 0><<<dim3(DI / 128, TT / 128), blk, 0, stream>>>(
      dtraw_bf, wdt_bf, dlt, TT, DI, DTR, DTR, dt_bias);

  // 5) chunked selective scan -> ybf
  scan_pass1<<<dim3(DI / 256, NCH, NB), blk, 0, stream>>>(
      dlt, xcv_bf, xdb, A_log, pmin, hend, Ssum);
  scan_pass2<<<(NB * DI * DS) / 256, blk, 0, stream>>>(hend, Ssum, A_log);
  scan_pass3<<<dim3(DI / 256, NCH, NB), blk, 0, stream>>>(
      dlt, xcv_bf, xdb, xz_bf, A_log, Dp, pmin, hend, ybf);

  // 6) out = y @ W_out^T  (2048x1024x2048) bf16 MFMA -> fp32 out
  gemm_bf16<64, 128, 0, 0><<<dim3(DM / 128, TT / 64), blk, 0, stream>>>(
      ybf, wout_bf, out, TT, DM, DI, DI, nullptr);
}

// Round 11
// 268.342 us; speedup vs baseline: 1.4602x; 1.4602x over previous
//
#include <hip/hip_runtime.h>
#include <hip/hip_bf16.h>
#include <math.h>

// Dims fixed by setup_inputs: d_model=1024, d_inner=2048, d_state=16,
// d_conv=4, dt_rank=64, B=2, L=1024. Tokens T = 2048.
#define DM 1024
#define DI 2048
#define DS 16
#define DTR 64
#define NB 2
#define LL 1024
#define TT (NB*LL)
#define SCH 16            // scan chunk length -> 1024 blocks -> 4/CU
#define NCH (LL/SCH)      // 64 chunks per sequence

typedef unsigned short u16;
typedef __attribute__((ext_vector_type(8))) short bf16x8;
typedef __attribute__((ext_vector_type(4))) float f32x4;

#define LOG2E 1.4426950408889634f

__device__ inline u16 f2bf(float f) {   // RNE f32->bf16
  union { float f; unsigned u; } c; c.f = f;
  unsigned u = c.u;
  return (u16)((u + 0x7fffu + ((u >> 16) & 1u)) >> 16);
}
__device__ inline float bf2f(u16 u) {
  union { unsigned u; float f; } c; c.u = ((unsigned)u) << 16;
  return c.f;
}

#define GLDS16(g, l) __builtin_amdgcn_global_load_lds( \
    (const __attribute__((address_space(1))) unsigned int*)(g), \
    (__attribute__((address_space(3))) unsigned int*)(l), 16, 0, 0)

// ---------------------------------------------------------------------------
// bf16 MFMA GEMM: C[M,N] = A[M,K]bf16 @ B[N,K]bf16^T. lda=ldb=K.
// kpb = K per z-block (split-K planes at C + z*M*N).
// EPI=1: clip(softplus(v+bias[col]),1e-4,20).  OB=1: store bf16, else fp32.
// ---------------------------------------------------------------------------
template<int BM, int BN, int EPI, int OB>
__global__ __launch_bounds__(256) void gemm_bf16(
    const u16* __restrict__ A, const u16* __restrict__ B,
    void* __restrict__ Cv, int M, int N, int K, int kpb,
    const float* __restrict__ bias) {
  constexpr int WAVES_M = BM / 64;
  constexpr int WAVES_N = 4 / WAVES_M;
  constexpr int WTM = 4;
  constexpr int WTN = BN / (WAVES_N * 16);
  constexpr int ASLABS = BM / 16;
  constexpr int SLABS = (BM + BN) / 16;
  constexpr int SPW = SLABS / 4;
  __shared__ u16 As[BM * 32];
  __shared__ u16 Bs[BN * 32];
  const int tid = threadIdx.x;
  const int wave = tid >> 6;
  const int lane = tid & 63;
  const int bm = blockIdx.y * BM;
  const int bn = blockIdx.x * BN;
  const int wm = (wave / WAVES_N) * 64;
  const int wn = (wave % WAVES_N) * (WTN * 16);
  const int r4 = lane >> 2;
  const int kc = (lane & 3) * 8;
  const int fr = lane & 15;
  const int fq = lane >> 4;
  const int koff = blockIdx.z * kpb;
  float* C = (float*)Cv + (size_t)blockIdx.z * M * N;
  u16* C16 = (u16*)Cv;

  f32x4 acc[WTM][WTN];
#pragma unroll
  for (int i = 0; i < WTM; ++i)
#pragma unroll
    for (int j = 0; j < WTN; ++j) acc[i][j] = (f32x4){0.f, 0.f, 0.f, 0.f};

  for (int k0 = koff; k0 < koff + kpb; k0 += 32) {
#pragma unroll
    for (int s = wave * SPW; s < (wave + 1) * SPW; ++s) {
      if (s < ASLABS) {
        int row = s * 16 + r4;
        GLDS16(A + (size_t)(bm + row) * K + k0 + kc, &As[s * 512]);
      } else {
        int row = (s - ASLABS) * 16 + r4;
        GLDS16(B + (size_t)(bn + row) * K + k0 + kc, &Bs[(s - ASLABS) * 512]);
      }
    }
    __syncthreads();
    bf16x8 af[WTM], bf[WTN];
#pragma unroll
    for (int i = 0; i < WTM; ++i)
      af[i] = *(const bf16x8*)&As[(wm + 16 * i + fr) * 32 + fq * 8];
#pragma unroll
    for (int j = 0; j < WTN; ++j)
      bf[j] = *(const bf16x8*)&Bs[(wn + 16 * j + fr) * 32 + fq * 8];
#pragma unroll
    for (int i = 0; i < WTM; ++i)
#pragma unroll
      for (int j = 0; j < WTN; ++j)
        acc[i][j] = __builtin_amdgcn_mfma_f32_16x16x32_bf16(af[i], bf[j], acc[i][j], 0, 0, 0);
    __syncthreads();
  }

#pragma unroll
  for (int i = 0; i < WTM; ++i) {
    int row0 = bm + wm + 16 * i + fq * 4;
#pragma unroll
    for (int j = 0; j < WTN; ++j) {
      int col = bn + wn + 16 * j + fr;
#pragma unroll
      for (int r = 0; r < 4; ++r) {
        float v = acc[i][j][r];
        if (EPI == 1) {
          v += bias[col];
          float sp = (v > 20.0f) ? v : log1pf(expf(v));
          v = fminf(fmaxf(sp, 1e-4f), 20.0f);
        }
        if (OB == 1) C16[(size_t)(row0 + r) * N + col] = f2bf(v);
        else         C[(size_t)(row0 + r) * N + col] = v;
      }
    }
  }
}

// ---------------------------------------------------------------------------
// GEMM3 split-K reduce: sum 16 planes of [TT x 128]; write fp32 xdb (96 cols),
// bf16 dt_raw (cols 0..63), and per-block partial min over Bm (cols 64..79).
// ---------------------------------------------------------------------------
__global__ __launch_bounds__(256) void gemm3_reduce(
    const float* __restrict__ part, float* __restrict__ xdb,
    u16* __restrict__ dtraw_bf, float* __restrict__ pmin) {
  int i = blockIdx.x * 256 + threadIdx.x;    // TT*128
  int t = i >> 7, col = i & 127;
  float s = 0.f;
#pragma unroll
  for (int z = 0; z < 16; ++z) s += part[(size_t)z * TT * 128 + i];
  if (col < 96) xdb[t * 96 + col] = s;
  if (col < 64) dtraw_bf[t * 64 + col] = f2bf(s);
  float mn = (col >= 64 && col < 80) ? s : 3.4e38f;
#pragma unroll
  for (int o = 32; o; o >>= 1) mn = fminf(mn, __shfl_down(mn, o));
  __shared__ float sm[4];
  if ((threadIdx.x & 63) == 0) sm[threadIdx.x >> 6] = mn;
  __syncthreads();
  if (threadIdx.x == 0)
    pmin[blockIdx.x] = fminf(fminf(sm[0], sm[1]), fminf(sm[2], sm[3]));
}

__global__ __launch_bounds__(256) void beta_fin(
    const float* __restrict__ pmin, float* __restrict__ beta) {
  float mn = 3.4e38f;
#pragma unroll
  for (int k = 0; k < 4; ++k) mn = fminf(mn, pmin[threadIdx.x + 256 * k]);
#pragma unroll
  for (int o = 32; o; o >>= 1) mn = fminf(mn, __shfl_down(mn, o));
  __shared__ float sm[4];
  if ((threadIdx.x & 63) == 0) sm[threadIdx.x >> 6] = mn;
  __syncthreads();
  if (threadIdx.x == 0)
    beta[0] = fmaxf(0.0f, -fminf(fminf(sm[0], sm[1]), fminf(sm[2], sm[3])));
}

// ---------------------------------------------------------------------------
// Fused bf16 casts: hs, W_in, W_out, W_x (pad to 128 rows), W_dt.
// ---------------------------------------------------------------------------
__global__ __launch_bounds__(256) void cast_all(
    const float* __restrict__ hs, const float* __restrict__ win,
    const float* __restrict__ wout, const float* __restrict__ wx,
    const float* __restrict__ wdt,
    u16* __restrict__ hs_bf, u16* __restrict__ win_bf,
    u16* __restrict__ wout_bf, u16* __restrict__ wx_bf,
    u16* __restrict__ wdt_bf) {
  int gid = blockIdx.x * 256 + threadIdx.x;  // 2,195,456 total
  const float* src; u16* dst; int off;
  if (gid < 524288)       { src = hs;   dst = hs_bf;   off = gid; }
  else if (gid < 1572864) { src = win;  dst = win_bf;  off = gid - 524288; }
  else if (gid < 2097152) { src = wout; dst = wout_bf; off = gid - 1572864; }
  else if (gid < 2146304) { src = wx;   dst = wx_bf;   off = gid - 2097152; }
  else if (gid < 2179072) { src = wdt;  dst = wdt_bf;  off = gid - 2146304; }
  else {  // zero-fill wx_bf rows 96..127
    ushort4 z4 = {0, 0, 0, 0};
    ((ushort4*)wx_bf)[49152 + gid - 2179072] = z4;
    return;
  }
  float4 v = ((const float4*)src)[off];
  ushort4 o;
  o.x = f2bf(v.x); o.y = f2bf(v.y); o.z = f2bf(v.z); o.w = f2bf(v.w);
  ((ushort4*)dst)[off] = o;
}

// ---------------------------------------------------------------------------
// Causal depthwise conv (k=4, pad 3) + bias + SiLU. bf16 in, bf16 out.
// ---------------------------------------------------------------------------
__global__ __launch_bounds__(256) void conv_silu4(
    const u16* __restrict__ xz, const float* __restrict__ w,
    const float* __restrict__ cb, u16* __restrict__ xc_bf) {
  int gid = blockIdx.x * 256 + threadIdx.x;  // TT*512
  int dq = (gid & 511) * 4;
  int t = gid >> 9;
  int l = t & (LL - 1);
  float wv[4][4];
#pragma unroll
  for (int j = 0; j < 4; ++j) {
    float4 ww = *(const float4*)&w[(dq + j) * 4];
    wv[j][0] = ww.x; wv[j][1] = ww.y; wv[j][2] = ww.z; wv[j][3] = ww.w;
  }
  float4 acc = *(const float4*)&cb[dq];
#pragma unroll
  for (int k = 0; k < 4; ++k) {
    int ll = l - 3 + k;
    if (ll < 0) continue;
    ushort4 xv = *(const ushort4*)&xz[(size_t)(t - 3 + k) * (2 * DI) + dq];
    acc.x += bf2f(xv.x) * wv[0][k]; acc.y += bf2f(xv.y) * wv[1][k];
    acc.z += bf2f(xv.z) * wv[2][k]; acc.w += bf2f(xv.w) * wv[3][k];
  }
  acc.x /= (1.0f + expf(-acc.x)); acc.y /= (1.0f + expf(-acc.y));
  acc.z /= (1.0f + expf(-acc.z)); acc.w /= (1.0f + expf(-acc.w));
  ushort4 o;
  o.x = f2bf(acc.x); o.y = f2bf(acc.y); o.z = f2bf(acc.z); o.w = f2bf(acc.w);
  *(ushort4*)&xc_bf[(size_t)t * DI + dq] = o;
}

// ---------------------------------------------------------------------------
// Chunked selective scan, SCH=16 (1024 blocks/pass -> 4/CU). 3 kernels.
// delta is fp32.
// ---------------------------------------------------------------------------
__global__ __launch_bounds__(256) void scan_pass1(
    const float* __restrict__ delta, const u16* __restrict__ xc_bf,
    const float* __restrict__ xdb, const float* __restrict__ A_log,
    const float* __restrict__ beta_p,
    float* __restrict__ hend, float* __restrict__ Ssum) {
  const int d = blockIdx.x * 256 + threadIdx.x;
  const int c = blockIdx.y;
  const int b = blockIdx.z;
  __shared__ float Bsh[SCH][16];
  const float beta = beta_p[0];
  const int t0 = b * LL + c * SCH;
  {
    int i = threadIdx.x;
    int tt = i >> 4, n = i & 15;
    Bsh[tt][n] = xdb[(size_t)(t0 + tt) * 96 + 64 + n] + beta;
  }
  __syncthreads();
  float Av2[16];
#pragma unroll
  for (int n = 0; n < 16; ++n) Av2[n] = expf(A_log[d * 16 + n]) * LOG2E;
  float h[16];
#pragma unroll
  for (int n = 0; n < 16; ++n) h[n] = 0.f;
  float S = 0.f;
  for (int tt = 0; tt < SCH; ++tt) {
    int t = t0 + tt;
    float dv = delta[(size_t)t * DI + d];
    float xv = bf2f(xc_bf[(size_t)t * DI + d]);
    float dx = dv * xv;
    S += dv;
#pragma unroll
    for (int n = 0; n < 16; ++n) {
      float a = __builtin_amdgcn_exp2f(-dv * Av2[n]);
      h[n] = a * h[n] + dx * Bsh[tt][n];
    }
  }
  size_t base = (((size_t)(b * NCH + c) * DI) + d) * 16;
#pragma unroll
  for (int n = 0; n < 16; ++n) hend[base + n] = h[n];
  Ssum[((size_t)(b * NCH + c) * DI) + d] = S;
}

__global__ __launch_bounds__(256) void scan_pass2(
    float* __restrict__ hend, const float* __restrict__ Ssum,
    const float* __restrict__ A_log) {
  int gid = blockIdx.x * 256 + threadIdx.x;   // 65536
  int n = gid & 15;
  int d = (gid >> 4) & (DI - 1);
  int b = gid >> 15;
  float Av2 = expf(A_log[d * 16 + n]) * LOG2E;
  float H = 0.f;
  for (int c = 0; c < NCH; ++c) {
    size_t cb = ((size_t)(b * NCH + c) * DI) + d;
    float hl = hend[cb * 16 + n];
    float p = __builtin_amdgcn_exp2f(-Av2 * Ssum[cb]);
    hend[cb * 16 + n] = H;
    H = p * H + hl;
  }
}

__global__ __launch_bounds__(256) void scan_pass3(
    const float* __restrict__ delta, const u16* __restrict__ xc_bf,
    const float* __restrict__ xdb, const u16* __restrict__ xz_bf,
    const float* __restrict__ A_log, const float* __restrict__ Dp,
    const float* __restrict__ beta_p, const float* __restrict__ hstart,
    u16* __restrict__ ybf) {
  const int d = blockIdx.x * 256 + threadIdx.x;
  const int c = blockIdx.y;
  const int b = blockIdx.z;
  __shared__ float Bsh[SCH][16];
  __shared__ float Csh[SCH][16];
  const float beta = beta_p[0];
  const int t0 = b * LL + c * SCH;
  {
    int i = threadIdx.x;
    int tt = i >> 4, n = i & 15;
    size_t row = (size_t)(t0 + tt) * 96;
    Bsh[tt][n] = xdb[row + 64 + n] + beta;
    Csh[tt][n] = xdb[row + 80 + n];
  }
  __syncthreads();
  float Av2[16];
#pragma unroll
  for (int n = 0; n < 16; ++n) Av2[n] = expf(A_log[d * 16 + n]) * LOG2E;
  float h[16];
  size_t base = (((size_t)(b * NCH + c) * DI) + d) * 16;
#pragma unroll
  for (int n = 0; n < 16; ++n) h[n] = hstart[base + n];
  const float Dd = Dp[d];
  for (int tt = 0; tt < SCH; ++tt) {
    int t = t0 + tt;
    float dv = delta[(size_t)t * DI + d];
    float xv = bf2f(xc_bf[(size_t)t * DI + d]);
    float dx = dv * xv;
    float yv = 0.f;
#pragma unroll
    for (int n = 0; n < 16; ++n) {
      float a = __builtin_amdgcn_exp2f(-dv * Av2[n]);
      h[n] = a * h[n] + dx * Bsh[tt][n];
      yv += h[n] * Csh[tt][n];
    }
    float zv = bf2f(xz_bf[(size_t)t * (2 * DI) + DI + d]);
    float out = (yv + xv * Dd) * (zv / (1.0f + expf(-zv)));
    ybf[(size_t)t * DI + d] = f2bf(out);
  }
}

extern "C" void kernel_launch(void* const* d_in, const int* in_sizes, int n_in,
                              void* d_out, int out_size, void* d_ws, size_t ws_size,
                              hipStream_t stream) {
  const float* hs      = (const float*)d_in[0];
  const float* W_in    = (const float*)d_in[1];
  const float* conv_w  = (const float*)d_in[2];
  const float* conv_b  = (const float*)d_in[3];
  const float* W_x     = (const float*)d_in[4];
  const float* W_dt    = (const float*)d_in[5];
  const float* dt_bias = (const float*)d_in[6];
  const float* W_out   = (const float*)d_in[7];
  const float* A_log   = (const float*)d_in[8];
  const float* Dp      = (const float*)d_in[9];
  float* out = (float*)d_out;

  float* ws       = (float*)d_ws;
  float* xz_bfR   = ws;                                  // 4,194,304 f
  float* xcv_bfR  = xz_bfR + (size_t)TT * 2 * DI / 2;    // 2,097,152 f
  float* xdb      = xcv_bfR + (size_t)TT * DI / 2;       //   196,608 f
  float* dlt      = xdb + (size_t)TT * 96;               // 4,194,304 f (= 16 planes TT*128)
  float* betab    = dlt + (size_t)TT * DI;               //        64 f
  float* pmin     = betab + 64;                          //     1,024 f
  float* hend     = pmin + 1024;                         // 4,194,304 f
  float* Ssum     = hend + (size_t)NB * NCH * DI * 16;   //   262,144 f
  float* hs_bfR   = Ssum + (size_t)NB * NCH * DI;        // 1,048,576 f
  float* win_bfR  = hs_bfR + (size_t)TT * DM / 2;        // 2,097,152 f
  float* wout_bfR = win_bfR + (size_t)2 * DI * DM / 2;   // 1,048,576 f
  float* wx_bfR   = wout_bfR + (size_t)DM * DI / 2;      //   131,072 f
  float* wdt_bfR  = wx_bfR + 131072;                     //    65,536 f
  float* dtraw_bfR = wdt_bfR + 65536;                    //    65,536 f

  u16* xz_bf    = (u16*)xz_bfR;
  u16* xcv_bf   = (u16*)xcv_bfR;
  u16* hs_bf    = (u16*)hs_bfR;
  u16* win_bf   = (u16*)win_bfR;
  u16* wout_bf  = (u16*)wout_bfR;
  u16* wx_bf    = (u16*)wx_bfR;
  u16* wdt_bf   = (u16*)wdt_bfR;
  u16* dtraw_bf = (u16*)dtraw_bfR;
  u16* ybf      = (u16*)win_bfR;   // aliases win_bf (dead after GEMM1)
  float* part   = dlt;             // GEMM3 planes (dead before GEMM5 writes dlt)

  dim3 blk(256);

  // 0) bf16 casts
  cast_all<<<8576, blk, 0, stream>>>(hs, W_in, W_out, W_x, W_dt,
                                     hs_bf, win_bf, wout_bf, wx_bf, wdt_bf);

  // 1) xz = hs @ W_in^T  (2048x4096x1024) bf16 MFMA -> bf16 out
  gemm_bf16<128, 128, 0, 1><<<dim3(4096 / 128, TT / 128), blk, 0, stream>>>(
      hs_bf, win_bf, xz_bf, TT, 2 * DI, DM, DM, nullptr);

  // 2) conv + silu -> xcv_bf
  conv_silu4<<<(TT * DI / 4) / 256, blk, 0, stream>>>(xz_bf, conv_w, conv_b, xcv_bf);

  // 3) x_dbl: (2048x128x2048) bf16 MFMA split-K=16 planes -> reduce (+min)
  gemm_bf16<128, 128, 0, 0><<<dim3(1, TT / 128, 16), blk, 0, stream>>>(
      xcv_bf, wx_bf, part, TT, 128, DI, 128, nullptr);
  gemm3_reduce<<<1024, blk, 0, stream>>>(part, xdb, dtraw_bf, pmin);

  // 4) beta
  beta_fin<<<1, blk, 0, stream>>>(pmin, betab);

  // 5) delta: (2048x2048x64) bf16 MFMA + softplus/clip epilogue -> fp32 dlt
  gemm_bf16<128, 128, 1, 0><<<dim3(DI / 128, TT / 128), blk, 0, stream>>>(
      dtraw_bf, wdt_bf, dlt, TT, DI, DTR, DTR, dt_bias);

  // 6) chunked selective scan -> ybf
  scan_pass1<<<dim3(DI / 256, NCH, NB), blk, 0, stream>>>(
      dlt, xcv_bf, xdb, A_log, betab, hend, Ssum);
  scan_pass2<<<(NB * DI * DS) / 256, blk, 0, stream>>>(hend, Ssum, A_log);
  scan_pass3<<<dim3(DI / 256, NCH, NB), blk, 0, stream>>>(
      dlt, xcv_bf, xdb, xz_bf, A_log, Dp, betab, hend, ybf);

  // 7) out = y @ W_out^T  (2048x1024x2048) bf16 MFMA -> fp32 out
  gemm_bf16<64, 128, 0, 0><<<dim3(DM / 128, TT / 64), blk, 0, stream>>>(
      ybf, wout_bf, out, TT, DM, DI, DI, nullptr);
}